// Round 10
// baseline (104.283 us; speedup 1.0000x reference)
//
#include <hip/hip_runtime.h>
#include <math.h>

// Problem constants (from reference): B=1024, C=256, H=W=24
static constexpr int B_N  = 1024;
static constexpr int C_N  = 256;
static constexpr int HW_N = 576;           // floats per channel = 144 float4
static constexpr float TEMP_INV = 1.0f / 0.07f;

static constexpr int GEMM_BLOCKS = 256;    // 64x64 tiles of the 1024x1024 logits

typedef __attribute__((ext_vector_type(8))) short bf16x8;
typedef __attribute__((ext_vector_type(4))) float f32x4;
typedef __attribute__((ext_vector_type(4))) float f4v;

// Control block in ws. part[i*16] (64B-strided, no false sharing) hold loss
// partials; ticket elects the finalizing block. Zeroed by pool block 0 (runs
// one launch earlier -> safe on every graph replay).
struct Ctrl {
    float    part[16 * 16];
    unsigned ticket;
};

// float -> bf16 round-to-nearest-even (inputs finite)
static __device__ __forceinline__ unsigned short f2bf(float f) {
    unsigned u = __float_as_uint(f);
    return (unsigned short)((u + 0x7FFFu + ((u >> 16) & 1u)) >> 16);
}
static __device__ __forceinline__ float bf2f(unsigned short h) {
    return __uint_as_float(((unsigned)h) << 16);
}

// ---------------------------------------------------------------------------
// Kernel A: pool (v3: group-per-channel lane mapping) + text normalize.
//  Blocks 0..31    : text rows (32/block): fp32 L2-normalize + bf16 -> Bb.
//                    Block 0 also zeroes the Ctrl partials + ticket.
//  Blocks 32..16415: pooling, 16 channels/block (4 waves x 4 channels).
//                    Each 16-lane group owns ONE channel: lane g*16+i reads
//                    f4 j*16+i (j=0..8) of channel g -- 144 f4 = 9/lane
//                    exactly. No select-accumulate (all data belongs to the
//                    lane's channel), and one shared 4-step intra-group
//                    shuffle reduces all 4 channels at once (vs 24 bpermutes
//                    before). ~50 issue slots per 9 KB loaded vs ~95 in v2.
//                    Coalescing: 4 x 256B segments = same 8 cache lines per
//                    load instruction as the old 1KB-contiguous pattern.
//                    Group lane 0 stores the channel's UNNORMALIZED bf16
//                    mean (normalization deferred to the GEMM).
// ---------------------------------------------------------------------------
__global__ __launch_bounds__(256) void pool_kernel(const float* __restrict__ img,
                                                   const float* __restrict__ text,
                                                   unsigned short* __restrict__ Ab,
                                                   unsigned short* __restrict__ Bb,
                                                   Ctrl* __restrict__ ctrl) {
    const int t    = threadIdx.x;
    const int w    = t >> 6;
    const int lane = t & 63;

    if (blockIdx.x < 32) {
        if (blockIdx.x == 0 && t < 17) {
            if (t < 16) ctrl->part[t * 16] = 0.0f;
            else        ctrl->ticket = 0u;
        }
        const int r0 = blockIdx.x * 32 + w * 8;
        #pragma unroll
        for (int rr = 0; rr < 8; ++rr) {
            const int r = r0 + rr;
            const f4v v = ((const f4v*)(text + (size_t)r * C_N))[lane];
            float ss = v.x * v.x + v.y * v.y + v.z * v.z + v.w * v.w;
            #pragma unroll
            for (int off = 32; off > 0; off >>= 1) ss += __shfl_xor(ss, off, 64);
            const float inv = 1.0f / fmaxf(sqrtf(ss), 1e-12f);   // matches F.normalize
            ushort4 o;
            o.x = f2bf(v.x * inv); o.y = f2bf(v.y * inv);
            o.z = f2bf(v.z * inv); o.w = f2bf(v.w * inv);
            ((ushort4*)(Bb + (size_t)r * C_N))[lane] = o;
        }
        return;
    }

    const int g   = blockIdx.x - 32;               // 0..16383, 16 channels each
    const int grp = lane >> 4;                     // 16-lane group -> channel
    const int i   = lane & 15;
    const size_t ch = (size_t)g * 16 + (size_t)w * 4 + grp;  // this lane's channel
    const f4v* src = (const f4v*)img + ch * 144;

    // 9 loads issued before any use (deep vmcnt pipe), all for OUR channel.
    f4v vv[9];
    #pragma unroll
    for (int j = 0; j < 9; ++j)
        vv[j] = __builtin_nontemporal_load(&src[j * 16 + i]);

    // Pairwise-tree sum of 36 floats (pure adds, no selects).
    float p[9];
    #pragma unroll
    for (int j = 0; j < 9; ++j)
        p[j] = (vv[j].x + vv[j].y) + (vv[j].z + vv[j].w);
    const float q0 = (p[0] + p[1]) + (p[2] + p[3]);
    const float q1 = (p[4] + p[5]) + (p[6] + p[7]);
    float s = (q0 + q1) + p[8];

    // One 4-step intra-group butterfly covers all 4 channels of the wave
    // (xor of lane bits 0..3 never crosses the 16-lane group boundary).
    #pragma unroll
    for (int off = 1; off < 16; off <<= 1) s += __shfl_xor(s, off, 64);

    if (i == 0)
        Ab[ch] = f2bf(s * (1.0f / (float)HW_N));   // unnormalized mean, bf16
}

// ---------------------------------------------------------------------------
// Kernel B (R9-proven, unchanged): bf16 MFMA GEMM, 64x64 tile, 256 blocks,
// 512 threads (8 waves -> 2 waves/SIMD latency overlap at 1 block/CU), whole
// K=256 staged once, XOR-swizzled. In-kernel deferred img-row norms; fused
// BCE loss; 16 padded partials + ticket finalize.
// Wave w (0..7): frag-row fr=w>>1, col-frags {cb, cb+1}, cb=(w&1)*2.
// ---------------------------------------------------------------------------
__global__ __launch_bounds__(512) void gemm_loss_kernel(const unsigned short* __restrict__ Ab,
                                                        const unsigned short* __restrict__ Bb,
                                                        const int* __restrict__ labels,
                                                        Ctrl* __restrict__ ctrl,
                                                        float* __restrict__ out) {
    __shared__ unsigned short Abuf[64 * 256];   // 32 KB, swizzled
    __shared__ unsigned short Bbuf[64 * 256];   // 32 KB, swizzled
    __shared__ float invA[64];
    __shared__ float red[8];

    const int t = threadIdx.x;
    const int rowBase = (blockIdx.x & 15) << 6;
    const int colBase = (blockIdx.x >> 4) << 6;

    // ---- Stage both 64x256 bf16 tiles. 2048 16B-chunks each, 4 per thread:
    // chunk c -> (row = c>>5, kc = c&31); LDS byte = (row*512+kc*16) ^ ((row&7)<<4).
    #pragma unroll
    for (int i = 0; i < 4; ++i) {
        const int c   = t + (i << 9);           // 0..2047
        const int row = c >> 5;
        const int kc  = c & 31;
        const unsigned off = (unsigned)((row << 9) + (kc << 4)) ^ (unsigned)((row & 7) << 4);
        uint4 va = ((const uint4*)(Ab + (size_t)(rowBase + row) * C_N))[kc];
        *(uint4*)((char*)Abuf + off) = va;
        uint4 vb = ((const uint4*)(Bb + (size_t)(colBase + row) * C_N))[kc];
        *(uint4*)((char*)Bbuf + off) = vb;
    }
    __syncthreads();

    // ---- Deferred normalization: inverse L2 norms of the 64 staged img rows.
    // Thread t -> row t>>3, eighth q = t&7 (4 chunks each).
    {
        const int row = t >> 3;
        const int q   = t & 7;
        float ss = 0.0f;
        #pragma unroll
        for (int j = 0; j < 4; ++j) {
            const int kc = (q << 2) + j;
            const unsigned off = (unsigned)((row << 9) + (kc << 4)) ^ (unsigned)((row & 7) << 4);
            const bf16x8 v = *(const bf16x8*)((char*)Abuf + off);
            #pragma unroll
            for (int e = 0; e < 8; ++e) {
                const float f = bf2f((unsigned short)v[e]);
                ss += f * f;
            }
        }
        ss += __shfl_xor(ss, 1, 64);              // combine the 8 eighth-rows
        ss += __shfl_xor(ss, 2, 64);
        ss += __shfl_xor(ss, 4, 64);
        if (q == 0) invA[row] = 1.0f / fmaxf(sqrtf(ss), 1e-12f);
    }
    __syncthreads();

    // ---- MFMA: wave w -> frag-row fr (16 rows), col-frags cb..cb+1.
    const int w    = t >> 6;                      // 0..7
    const int lane = t & 63;
    const int m16  = lane & 15;
    const int kg   = lane >> 4;
    const int fr   = w >> 1;                      // 0..3
    const int cb   = (w & 1) << 1;                // 0 or 2

    f32x4 acc[2] = {{0.f, 0.f, 0.f, 0.f}, {0.f, 0.f, 0.f, 0.f}};
    #pragma unroll
    for (int s = 0; s < 8; ++s) {                 // K = 256 = 8 * 32
        const int kc   = (s << 2) + kg;
        const int arow = (fr << 4) + m16;
        const bf16x8 a = *(const bf16x8*)((char*)Abuf +
                            (((unsigned)((arow << 9) + (kc << 4))) ^ (unsigned)((arow & 7) << 4)));
        #pragma unroll
        for (int ct = 0; ct < 2; ++ct) {
            const int brow = ((cb + ct) << 4) + m16;
            const bf16x8 b = *(const bf16x8*)((char*)Bbuf +
                                (((unsigned)((brow << 9) + (kc << 4))) ^ (unsigned)((brow & 7) << 4)));
            acc[ct] = __builtin_amdgcn_mfma_f32_16x16x32_bf16(a, b, acc[ct], 0, 0, 0);
        }
    }

    // ---- Epilogue. D frag: col = lane&15, row = (lane>>4)*4 + reg [m89/m91].
    float lsum = 0.0f;
    const int lr0 = (fr << 4) + (kg << 2);        // tile-local row of acc reg 0
    #pragma unroll
    for (int ct = 0; ct < 2; ++ct) {
        const int gj   = colBase + ((cb + ct) << 4) + m16;
        const int labj = labels[gj];
        #pragma unroll
        for (int r = 0; r < 4; ++r) {
            const float sA = invA[lr0 + r] * TEMP_INV;
            const float x  = acc[ct][r] * sA;
            const float z  = (labels[rowBase + lr0 + r] == labj) ? 1.0f : 0.0f;
            const float sp = fmaxf(x, 0.0f) + __logf(1.0f + __expf(-fabsf(x)));
            lsum += sp - x * z;
        }
    }
    #pragma unroll
    for (int off = 32; off > 0; off >>= 1) lsum += __shfl_xor(lsum, off, 64);
    if (lane == 0) red[w] = lsum;
    __syncthreads();

    if (w == 0) {
        const float bsum = (red[0] + red[1]) + (red[2] + red[3])
                         + (red[4] + red[5]) + (red[6] + red[7]);
        unsigned old = 0u;
        if (lane == 0) {
            atomicAdd(&ctrl->part[(blockIdx.x & 15) << 4], bsum);
            __threadfence();
            old = atomicAdd(&ctrl->ticket, 1u);
        }
        old = __shfl(old, 0, 64);
        if (old == (unsigned)(GEMM_BLOCKS - 1)) {  // last block: finalize
            float v = 0.0f;
            if (lane < 16)
                v = __hip_atomic_load(&ctrl->part[lane << 4], __ATOMIC_ACQUIRE,
                                      __HIP_MEMORY_SCOPE_AGENT);
            #pragma unroll
            for (int off = 8; off > 0; off >>= 1) v += __shfl_xor(v, off, 64);
            if (lane == 0)
                out[0] = v * (1.0f / ((float)B_N * (float)B_N));
        }
    }
}

extern "C" void kernel_launch(void* const* d_in, const int* in_sizes, int n_in,
                              void* d_out, int out_size, void* d_ws, size_t ws_size,
                              hipStream_t stream) {
    const float* img    = (const float*)d_in[0];   // [1024,256,24,24] fp32
    const float* text   = (const float*)d_in[1];   // [1024,256] fp32
    const int*   labels = (const int*)d_in[2];     // [1024] int32 (JAX demotes int64)
    float* out = (float*)d_out;

    char* ws = (char*)d_ws;
    unsigned short* Ab   = (unsigned short*)ws;                 // 512 KiB bf16 (unnormalized means)
    unsigned short* Bb   = (unsigned short*)(ws + (512 << 10)); // 512 KiB bf16 (normalized text)
    Ctrl*           ctrl = (Ctrl*)(ws + (1 << 20));             // ~1 KiB control

    pool_kernel<<<32 + 16384, 256, 0, stream>>>(img, text, Ab, Bb, ctrl);
    gemm_loss_kernel<<<GEMM_BLOCKS, 512, 0, stream>>>(Ab, Bb, labels, ctrl, out);
}